// Round 1
// baseline (967.648 us; speedup 1.0000x reference)
//
#include <hip/hip_runtime.h>
#include <hip/hip_bf16.h>
#include <math.h>

#define N_SRC   100000
#define N_DST   100000
#define N_EDGES 1600000
#define IN_F    256
#define HEADS   4
#define D_OUT   64
#define NHD     256           // HEADS * D_OUT
#define NEG_SLOPE 0.2f

// ---------------------------------------------------------------------------
// Kernel 1: wr[k][h] = sum_d W[k][h*64+d] * attn_r[h][d]   (256x4 result)
// ---------------------------------------------------------------------------
__global__ void k_wr(const float* __restrict__ W, const float* __restrict__ ar,
                     float* __restrict__ wr) {
    __shared__ float a[NHD];
    int t = threadIdx.x;                 // 256 threads, 1 block
    a[t] = ar[t];
    __syncthreads();
    // thread t owns W row t
    float s[HEADS] = {0.f, 0.f, 0.f, 0.f};
    for (int h = 0; h < HEADS; ++h) {
        float acc = 0.f;
        #pragma unroll 8
        for (int d = 0; d < D_OUT; ++d)
            acc += W[t * NHD + h * D_OUT + d] * a[h * D_OUT + d];
        s[h] = acc;
    }
    *(float4*)&wr[t * 4] = make_float4(s[0], s[1], s[2], s[3]);
}

// ---------------------------------------------------------------------------
// Kernel 2: er[n][h] = sum_k feat_dst[n][k] * wr[k][h]   (one wave per node)
// ---------------------------------------------------------------------------
__global__ __launch_bounds__(256) void k_er(const float* __restrict__ fdst,
                                            const float* __restrict__ wr,
                                            float* __restrict__ er) {
    __shared__ float4 wrs[256];          // wr row k as float4 over h
    int t = threadIdx.x;
    wrs[t] = ((const float4*)wr)[t];
    __syncthreads();
    int node = blockIdx.x * 4 + (t >> 6);
    int lane = t & 63;
    float4 f = *(const float4*)&fdst[(size_t)node * IN_F + lane * 4];
    float4 w0 = wrs[lane * 4 + 0], w1 = wrs[lane * 4 + 1];
    float4 w2 = wrs[lane * 4 + 2], w3 = wrs[lane * 4 + 3];
    float px = f.x * w0.x + f.y * w1.x + f.z * w2.x + f.w * w3.x;
    float py = f.x * w0.y + f.y * w1.y + f.z * w2.y + f.w * w3.y;
    float pz = f.x * w0.z + f.y * w1.z + f.z * w2.z + f.w * w3.z;
    float pw = f.x * w0.w + f.y * w1.w + f.z * w2.w + f.w * w3.w;
    #pragma unroll
    for (int m = 1; m < 64; m <<= 1) {
        px += __shfl_xor(px, m);
        py += __shfl_xor(py, m);
        pz += __shfl_xor(pz, m);
        pw += __shfl_xor(pw, m);
    }
    if (lane == 0)
        *(float4*)&er[node * 4] = make_float4(px, py, pz, pw);
}

// ---------------------------------------------------------------------------
// Kernel 3: fsrc = feat_src @ W   (f32 vector-ALU GEMM, 64x64 tile, 4x4/thread)
// ---------------------------------------------------------------------------
#define BM 64
#define BN 64
#define BK 16
__global__ __launch_bounds__(256) void k_gemm(const float* __restrict__ A,
                                              const float* __restrict__ B,
                                              float* __restrict__ C, int M) {
    __shared__ float As[BK][BM + 4];     // A^T stored: As[kk][m]
    __shared__ float Bs[BK][BN];
    int m0 = blockIdx.y * BM, n0 = blockIdx.x * BN;
    int t = threadIdx.x;
    int tx = t & 15, ty = t >> 4;
    float acc[4][4] = {};
    for (int k0 = 0; k0 < IN_F; k0 += BK) {
        // stage A: 64 rows x 16 cols, one float4 per thread
        {
            int r = t >> 2, c = (t & 3) * 4;
            int gm = m0 + r;
            float4 v = make_float4(0.f, 0.f, 0.f, 0.f);
            if (gm < M) v = *(const float4*)&A[(size_t)gm * IN_F + k0 + c];
            As[c + 0][r] = v.x; As[c + 1][r] = v.y;
            As[c + 2][r] = v.z; As[c + 3][r] = v.w;
        }
        // stage B: 16 rows x 64 cols, one float4 per thread
        {
            int kr = t >> 4, cc = (t & 15) * 4;
            *(float4*)&Bs[kr][cc] = *(const float4*)&B[(size_t)(k0 + kr) * NHD + n0 + cc];
        }
        __syncthreads();
        #pragma unroll
        for (int kk = 0; kk < BK; ++kk) {
            float4 a = *(const float4*)&As[kk][ty * 4];
            float4 b = *(const float4*)&Bs[kk][tx * 4];
            float av[4] = {a.x, a.y, a.z, a.w};
            float bv[4] = {b.x, b.y, b.z, b.w};
            #pragma unroll
            for (int i = 0; i < 4; ++i)
                #pragma unroll
                for (int j = 0; j < 4; ++j)
                    acc[i][j] += av[i] * bv[j];
        }
        __syncthreads();
    }
    #pragma unroll
    for (int i = 0; i < 4; ++i) {
        int gm = m0 + ty * 4 + i;
        if (gm < M)
            *(float4*)&C[(size_t)gm * NHD + n0 + tx * 4] =
                make_float4(acc[i][0], acc[i][1], acc[i][2], acc[i][3]);
    }
}

// ---------------------------------------------------------------------------
// Kernel 4: el[n][h] = sum_d fsrc[n][h*64+d] * attn_l[h][d]  (one wave/node)
// ---------------------------------------------------------------------------
__global__ __launch_bounds__(256) void k_el(const float* __restrict__ fsrc,
                                            const float* __restrict__ al_g,
                                            float* __restrict__ el) {
    __shared__ float al[NHD];
    int t = threadIdx.x;
    al[t] = al_g[t];
    __syncthreads();
    int node = blockIdx.x * 4 + (t >> 6);
    int lane = t & 63;
    float4 f = *(const float4*)&fsrc[(size_t)node * NHD + lane * 4];
    float s = f.x * al[lane * 4] + f.y * al[lane * 4 + 1] +
              f.z * al[lane * 4 + 2] + f.w * al[lane * 4 + 3];
    #pragma unroll
    for (int m = 1; m < 16; m <<= 1) s += __shfl_xor(s, m);
    if ((lane & 15) == 0) el[node * 4 + (lane >> 4)] = s;
}

// ---------------------------------------------------------------------------
// Edge histogram over dst
// ---------------------------------------------------------------------------
__global__ void k_hist(const int* __restrict__ edst, int* __restrict__ deg) {
    int e = blockIdx.x * 256 + threadIdx.x;
    if (e < N_EDGES) atomicAdd(&deg[edst[e]], 1);
}

// ---------------------------------------------------------------------------
// 3-kernel exclusive scan over deg[N_DST] -> off[N_DST+1]
// ---------------------------------------------------------------------------
#define SCAN_B 1024
__global__ __launch_bounds__(SCAN_B) void k_scanA(const int* __restrict__ deg,
                                                  int* __restrict__ off,
                                                  int* __restrict__ bsum) {
    int t = threadIdx.x, b = blockIdx.x;
    int i = b * SCAN_B + t;
    int v = (i < N_DST) ? deg[i] : 0;
    int incl = v;
    int lane = t & 63, w = t >> 6;
    #pragma unroll
    for (int d = 1; d < 64; d <<= 1) {
        int u = __shfl_up(incl, d);
        if (lane >= d) incl += u;
    }
    __shared__ int ws[16];
    if (lane == 63) ws[w] = incl;
    __syncthreads();
    if (t == 0) {
        int run = 0;
        for (int j = 0; j < 16; ++j) { int x = ws[j]; ws[j] = run; run += x; }
        bsum[b] = run;
    }
    __syncthreads();
    if (i < N_DST) off[i] = incl - v + ws[w];
}

__global__ void k_scanB(int* __restrict__ bsum, int nb) {
    if (threadIdx.x == 0 && blockIdx.x == 0) {
        int run = 0;
        for (int j = 0; j < nb; ++j) { int x = bsum[j]; bsum[j] = run; run += x; }
    }
}

__global__ __launch_bounds__(SCAN_B) void k_scanC(int* __restrict__ off,
                                                  const int* __restrict__ bsum) {
    int t = threadIdx.x, b = blockIdx.x;
    int i = b * SCAN_B + t;
    if (i < N_DST) off[i] += bsum[b];
    if (i == 0) off[N_DST] = N_EDGES;
}

// ---------------------------------------------------------------------------
// Scatter: counting-sort edges by dst; compute s = exp(leaky(el[src]+er[dst]))
// ---------------------------------------------------------------------------
__global__ void k_scatter(const int* __restrict__ esrc, const int* __restrict__ edst,
                          const float* __restrict__ el, const float* __restrict__ er,
                          const int* __restrict__ off, int* __restrict__ cursor,
                          int* __restrict__ ssrc, float4* __restrict__ ss) {
    int e = blockIdx.x * 256 + threadIdx.x;
    if (e >= N_EDGES) return;
    int src = esrc[e], dst = edst[e];
    float4 l4 = *(const float4*)&el[src * 4];
    float4 r4 = *(const float4*)&er[dst * 4];
    float ex = l4.x + r4.x, ey = l4.y + r4.y, ez = l4.z + r4.z, ew = l4.w + r4.w;
    ex = (ex >= 0.f) ? ex : NEG_SLOPE * ex;
    ey = (ey >= 0.f) ? ey : NEG_SLOPE * ey;
    ez = (ez >= 0.f) ? ez : NEG_SLOPE * ez;
    ew = (ew >= 0.f) ? ew : NEG_SLOPE * ew;
    float4 s = make_float4(expf(ex), expf(ey), expf(ez), expf(ew));
    int pos = off[dst] + atomicAdd(&cursor[dst], 1);
    ssrc[pos] = src;
    ss[pos] = s;
}

// ---------------------------------------------------------------------------
// Aggregation: one block (256 thr) per dst node. No float atomics.
// thread t -> output column t (h = t>>6, d = t&63)
// ---------------------------------------------------------------------------
__global__ __launch_bounds__(256) void k_agg(const int* __restrict__ off,
                                             const int* __restrict__ ssrc,
                                             const float* __restrict__ ss,
                                             const float* __restrict__ fsrc,
                                             float* __restrict__ out) {
    int b = blockIdx.x;
    int t = threadIdx.x;
    int s0 = off[b], s1 = off[b + 1];
    __shared__ float inv_den[HEADS];
    if (t < 64) {
        int h = t & 3;
        float p = 0.f;
        for (int i = s0 + (t >> 2); i < s1; i += 16)
            p += ss[(size_t)i * 4 + h];
        #pragma unroll
        for (int m = 4; m < 64; m <<= 1) p += __shfl_xor(p, m);
        if (t < 4) inv_den[t] = (p > 0.f) ? (1.0f / p) : 0.f;
    }
    __syncthreads();
    int h = t >> 6;
    float idh = inv_den[h];
    float acc = 0.f;
    for (int i = s0; i < s1; ++i) {
        int src = ssrc[i];                               // broadcast load
        float a = ss[(size_t)i * 4 + h] * idh;           // broadcast per 64
        acc += a * fsrc[(size_t)src * NHD + t];          // coalesced 1KB/edge
    }
    out[(size_t)b * NHD + t] = acc;
}

// ---------------------------------------------------------------------------
// Launch
// ---------------------------------------------------------------------------
extern "C" void kernel_launch(void* const* d_in, const int* in_sizes, int n_in,
                              void* d_out, int out_size, void* d_ws, size_t ws_size,
                              hipStream_t stream) {
    const float* feat_src = (const float*)d_in[0];
    const float* feat_dst = (const float*)d_in[1];
    const int*   edge_src = (const int*)d_in[2];
    const int*   edge_dst = (const int*)d_in[3];
    const float* W        = (const float*)d_in[4];
    const float* attn_l   = (const float*)d_in[5];
    const float* attn_r   = (const float*)d_in[6];
    float* out = (float*)d_out;

    char* base = (char*)d_ws;
    float* fsrc     = (float*)(base);                         // 102,400,000 B
    float* sorted_s = (float*)(base + 102400000);             //  25,600,000 B
    float* el       = (float*)(base + 128000000);             //   1,600,000 B
    float* er       = (float*)(base + 129600000);             //   1,600,000 B
    float* wr       = (float*)(base + 131200000);             //       4,096 B
    int*   deg      = (int*)  (base + 131204096);             //     400,000 B
    int*   off      = (int*)  (base + 131604096);             //     400,016 B
    int*   cursor   = (int*)  (base + 132004112);             //     400,000 B
    int*   bsum     = (int*)  (base + 132404112);             //         512 B
    int*   ssrc     = (int*)  (base + 132404624);             //   6,400,000 B

    hipMemsetAsync(deg, 0, N_DST * sizeof(int), stream);
    hipMemsetAsync(cursor, 0, N_DST * sizeof(int), stream);

    // wr = fold attn_r into W (256x4)
    k_wr<<<1, 256, 0, stream>>>(W, attn_r, wr);
    // er = feat_dst @ wr
    k_er<<<N_DST / 4, 256, 0, stream>>>(feat_dst, wr, er);
    // fsrc = feat_src @ W
    dim3 ggrid(NHD / BN, (N_SRC + BM - 1) / BM);
    k_gemm<<<ggrid, 256, 0, stream>>>(feat_src, W, fsrc, N_SRC);
    // el from fsrc
    k_el<<<N_SRC / 4, 256, 0, stream>>>(fsrc, attn_l, el);
    // CSR build
    k_hist<<<(N_EDGES + 255) / 256, 256, 0, stream>>>(edge_dst, deg);
    int nb = (N_DST + SCAN_B - 1) / SCAN_B;                   // 98
    k_scanA<<<nb, SCAN_B, 0, stream>>>(deg, off, bsum);
    k_scanB<<<1, 64, 0, stream>>>(bsum, nb);
    k_scanC<<<nb, SCAN_B, 0, stream>>>(off, bsum);
    k_scatter<<<(N_EDGES + 255) / 256, 256, 0, stream>>>(
        edge_src, edge_dst, el, er, off, cursor, ssrc, (float4*)sorted_s);
    // aggregate per dst node
    k_agg<<<N_DST, 256, 0, stream>>>(off, ssrc, sorted_s, fsrc, out);
}

// Round 2
// 735.378 us; speedup vs baseline: 1.3159x; 1.3159x over previous
//
#include <hip/hip_runtime.h>
#include <hip/hip_bf16.h>
#include <math.h>

#define N_SRC   100000
#define N_DST   100000
#define N_EDGES 1600000
#define IN_F    256
#define HEADS   4
#define D_OUT   64
#define NHD     256           // HEADS * D_OUT
#define NEG_SLOPE 0.2f

typedef __attribute__((ext_vector_type(8))) short          bf16x8;
typedef __attribute__((ext_vector_type(8))) unsigned short u16x8;
typedef __attribute__((ext_vector_type(4))) float          f32x4;

// f32 -> bf16 (RNE) + residual bf16
__device__ inline void split_bf16(float x, unsigned short& h, unsigned short& l) {
    unsigned u = __float_as_uint(x);
    unsigned uh = u + (0x7fffu + ((u >> 16) & 1u));
    h = (unsigned short)(uh >> 16);
    float hf = __uint_as_float(uh & 0xffff0000u);
    float r = x - hf;
    unsigned ur = __float_as_uint(r);
    l = (unsigned short)((ur + (0x7fffu + ((ur >> 16) & 1u))) >> 16);
}

// ---------------------------------------------------------------------------
// Kernel 1: wr[k][h] = sum_d W[k][h*64+d] * attn_r[h][d]   (256x4 result)
// ---------------------------------------------------------------------------
__global__ void k_wr(const float* __restrict__ W, const float* __restrict__ ar,
                     float* __restrict__ wr) {
    __shared__ float a[NHD];
    int t = threadIdx.x;                 // 256 threads, 1 block
    a[t] = ar[t];
    __syncthreads();
    float s[HEADS] = {0.f, 0.f, 0.f, 0.f};
    for (int h = 0; h < HEADS; ++h) {
        float acc = 0.f;
        #pragma unroll 8
        for (int d = 0; d < D_OUT; ++d)
            acc += W[t * NHD + h * D_OUT + d] * a[h * D_OUT + d];
        s[h] = acc;
    }
    *(float4*)&wr[t * 4] = make_float4(s[0], s[1], s[2], s[3]);
}

// ---------------------------------------------------------------------------
// Kernel 1b: W -> transposed hi/lo bf16:  Wht[n][k], Wlt[n][k]
// ---------------------------------------------------------------------------
__global__ void k_wcast(const float* __restrict__ W,
                        unsigned short* __restrict__ Wht,
                        unsigned short* __restrict__ Wlt) {
    int n = blockIdx.x;      // 256 blocks
    int k = threadIdx.x;     // 256 threads
    float x = W[k * NHD + n];
    unsigned short h, l;
    split_bf16(x, h, l);
    Wht[n * IN_F + k] = h;
    Wlt[n * IN_F + k] = l;
}

// ---------------------------------------------------------------------------
// Kernel 2: er[n][h] = sum_k feat_dst[n][k] * wr[k][h]   (one wave per node)
// ---------------------------------------------------------------------------
__global__ __launch_bounds__(256) void k_er(const float* __restrict__ fdst,
                                            const float* __restrict__ wr,
                                            float* __restrict__ er) {
    __shared__ float4 wrs[256];
    int t = threadIdx.x;
    wrs[t] = ((const float4*)wr)[t];
    __syncthreads();
    int node = blockIdx.x * 4 + (t >> 6);
    int lane = t & 63;
    float4 f = *(const float4*)&fdst[(size_t)node * IN_F + lane * 4];
    float4 w0 = wrs[lane * 4 + 0], w1 = wrs[lane * 4 + 1];
    float4 w2 = wrs[lane * 4 + 2], w3 = wrs[lane * 4 + 3];
    float px = f.x * w0.x + f.y * w1.x + f.z * w2.x + f.w * w3.x;
    float py = f.x * w0.y + f.y * w1.y + f.z * w2.y + f.w * w3.y;
    float pz = f.x * w0.z + f.y * w1.z + f.z * w2.z + f.w * w3.z;
    float pw = f.x * w0.w + f.y * w1.w + f.z * w2.w + f.w * w3.w;
    #pragma unroll
    for (int m = 1; m < 64; m <<= 1) {
        px += __shfl_xor(px, m);
        py += __shfl_xor(py, m);
        pz += __shfl_xor(pz, m);
        pw += __shfl_xor(pw, m);
    }
    if (lane == 0)
        *(float4*)&er[node * 4] = make_float4(px, py, pz, pw);
}

// ---------------------------------------------------------------------------
// Kernel 3: fsrc = feat_src @ W via split-bf16 MFMA (3 products, fp32 acc)
//           + fused el[n][h] epilogue.
// BM=128, BN=256(all of N), BK=32, 512 thr = 8 waves (2Mx4N), wave tile 64x64.
// ---------------------------------------------------------------------------
#define GBM 128
#define GBK 32
__global__ __launch_bounds__(512, 2) void k_gemm_mfma(
        const float* __restrict__ A, const unsigned short* __restrict__ Bht,
        const unsigned short* __restrict__ Blt, const float* __restrict__ al_g,
        float* __restrict__ C, float* __restrict__ el) {
    __shared__ __align__(16) unsigned short Ah[GBM][GBK], Al[GBM][GBK];
    __shared__ __align__(16) unsigned short Bh[NHD][GBK], Bl[NHD][GBK];
    const int t = threadIdx.x;
    const int m0 = blockIdx.x * GBM;
    const int wid = t >> 6, lane = t & 63;
    const int wm = wid >> 2, wn = wid & 3;       // wave tile: rows wm*64, cols wn*64
    const int fr = lane & 15, fq = lane >> 4;
    const int kb = fq * 8;                        // k-offset of this lane's frag

    f32x4 acc[4][4];
    #pragma unroll
    for (int m = 0; m < 4; ++m)
        #pragma unroll
        for (int n = 0; n < 4; ++n)
            acc[m][n] = (f32x4){0.f, 0.f, 0.f, 0.f};

    // staging assignments
    const int ar = t >> 2, ac = (t & 3) * 8;      // A: row 0..127, col {0,8,16,24}
    const bool avalid = (m0 + ar) < N_SRC;
    const float* aptr = A + (size_t)(m0 + ar) * IN_F + ac;
    const int bn = t >> 1, bk = (t & 1) * 16;     // B: n 0..255, k {0,16}

    for (int k0 = 0; k0 < IN_F; k0 += GBK) {
        // ---- load globals to regs ----
        float4 v0 = make_float4(0.f, 0.f, 0.f, 0.f), v1 = v0;
        if (avalid) {
            v0 = *(const float4*)(aptr + k0);
            v1 = *(const float4*)(aptr + k0 + 4);
        }
        u16x8 bh0 = *(const u16x8*)(Bht + (size_t)bn * IN_F + k0 + bk);
        u16x8 bh1 = *(const u16x8*)(Bht + (size_t)bn * IN_F + k0 + bk + 8);
        u16x8 bl0 = *(const u16x8*)(Blt + (size_t)bn * IN_F + k0 + bk);
        u16x8 bl1 = *(const u16x8*)(Blt + (size_t)bn * IN_F + k0 + bk + 8);
        // ---- convert A to hi/lo ----
        float xs[8] = {v0.x, v0.y, v0.z, v0.w, v1.x, v1.y, v1.z, v1.w};
        u16x8 hv, lv;
        #pragma unroll
        for (int j = 0; j < 8; ++j) {
            unsigned short hh, ll;
            split_bf16(xs[j], hh, ll);
            hv[j] = hh; lv[j] = ll;
        }
        __syncthreads();                 // readers of previous chunk done
        *(u16x8*)&Ah[ar][ac] = hv;
        *(u16x8*)&Al[ar][ac] = lv;
        *(u16x8*)&Bh[bn][bk]     = bh0;
        *(u16x8*)&Bh[bn][bk + 8] = bh1;
        *(u16x8*)&Bl[bn][bk]     = bl0;
        *(u16x8*)&Bl[bn][bk + 8] = bl1;
        __syncthreads();                 // writes visible
        // ---- fragments ----
        bf16x8 afh[4], afl[4], bfh[4], bfl[4];
        #pragma unroll
        for (int m = 0; m < 4; ++m) {
            afh[m] = *(const bf16x8*)&Ah[wm * 64 + m * 16 + fr][kb];
            afl[m] = *(const bf16x8*)&Al[wm * 64 + m * 16 + fr][kb];
        }
        #pragma unroll
        for (int n = 0; n < 4; ++n) {
            bfh[n] = *(const bf16x8*)&Bh[wn * 64 + n * 16 + fr][kb];
            bfl[n] = *(const bf16x8*)&Bl[wn * 64 + n * 16 + fr][kb];
        }
        #pragma unroll
        for (int m = 0; m < 4; ++m)
            #pragma unroll
            for (int n = 0; n < 4; ++n) {
                acc[m][n] = __builtin_amdgcn_mfma_f32_16x16x32_bf16(afh[m], bfh[n], acc[m][n], 0, 0, 0);
                acc[m][n] = __builtin_amdgcn_mfma_f32_16x16x32_bf16(afh[m], bfl[n], acc[m][n], 0, 0, 0);
                acc[m][n] = __builtin_amdgcn_mfma_f32_16x16x32_bf16(afl[m], bfh[n], acc[m][n], 0, 0, 0);
            }
    }

    // ---- epilogue: store C + fused el (this wave's 64 cols == head wn) ----
    float alw[4];
    #pragma unroll
    for (int n = 0; n < 4; ++n) alw[n] = al_g[wn * 64 + n * 16 + fr];
    #pragma unroll
    for (int m = 0; m < 4; ++m) {
        int rbase = m0 + wm * 64 + m * 16 + fq * 4;
        float elp[4] = {0.f, 0.f, 0.f, 0.f};
        #pragma unroll
        for (int n = 0; n < 4; ++n) {
            f32x4 a = acc[m][n];
            int col = wn * 64 + n * 16 + fr;
            float w = alw[n];
            elp[0] += a[0] * w; elp[1] += a[1] * w;
            elp[2] += a[2] * w; elp[3] += a[3] * w;
            #pragma unroll
            for (int j = 0; j < 4; ++j)
                if (rbase + j < N_SRC)
                    C[(size_t)(rbase + j) * NHD + col] = a[j];
        }
        #pragma unroll
        for (int j = 0; j < 4; ++j) {
            float s = elp[j];
            s += __shfl_xor(s, 1); s += __shfl_xor(s, 2);
            s += __shfl_xor(s, 4); s += __shfl_xor(s, 8);
            if (fr == 0 && rbase + j < N_SRC)
                el[(rbase + j) * HEADS + wn] = s;
        }
    }
}

// ---------------------------------------------------------------------------
// Edge histogram over dst
// ---------------------------------------------------------------------------
__global__ void k_hist(const int* __restrict__ edst, int* __restrict__ deg) {
    int e = blockIdx.x * 256 + threadIdx.x;
    if (e < N_EDGES) atomicAdd(&deg[edst[e]], 1);
}

// ---------------------------------------------------------------------------
// 3-kernel exclusive scan over deg[N_DST] -> off[N_DST+1]
// ---------------------------------------------------------------------------
#define SCAN_B 1024
__global__ __launch_bounds__(SCAN_B) void k_scanA(const int* __restrict__ deg,
                                                  int* __restrict__ off,
                                                  int* __restrict__ bsum) {
    int t = threadIdx.x, b = blockIdx.x;
    int i = b * SCAN_B + t;
    int v = (i < N_DST) ? deg[i] : 0;
    int incl = v;
    int lane = t & 63, w = t >> 6;
    #pragma unroll
    for (int d = 1; d < 64; d <<= 1) {
        int u = __shfl_up(incl, d);
        if (lane >= d) incl += u;
    }
    __shared__ int ws[16];
    if (lane == 63) ws[w] = incl;
    __syncthreads();
    if (t == 0) {
        int run = 0;
        for (int j = 0; j < 16; ++j) { int x = ws[j]; ws[j] = run; run += x; }
        bsum[b] = run;
    }
    __syncthreads();
    if (i < N_DST) off[i] = incl - v + ws[w];
}

__global__ void k_scanB(int* __restrict__ bsum, int nb) {
    if (threadIdx.x == 0 && blockIdx.x == 0) {
        int run = 0;
        for (int j = 0; j < nb; ++j) { int x = bsum[j]; bsum[j] = run; run += x; }
    }
}

__global__ __launch_bounds__(SCAN_B) void k_scanC(int* __restrict__ off,
                                                  const int* __restrict__ bsum) {
    int t = threadIdx.x, b = blockIdx.x;
    int i = b * SCAN_B + t;
    if (i < N_DST) off[i] += bsum[b];
    if (i == 0) off[N_DST] = N_EDGES;
}

// ---------------------------------------------------------------------------
// Scatter: counting-sort edges by dst; compute s = exp(leaky(el[src]+er[dst]))
// ---------------------------------------------------------------------------
__global__ void k_scatter(const int* __restrict__ esrc, const int* __restrict__ edst,
                          const float* __restrict__ el, const float* __restrict__ er,
                          const int* __restrict__ off, int* __restrict__ cursor,
                          int* __restrict__ ssrc, float4* __restrict__ ss) {
    int e = blockIdx.x * 256 + threadIdx.x;
    if (e >= N_EDGES) return;
    int src = esrc[e], dst = edst[e];
    float4 l4 = *(const float4*)&el[src * 4];
    float4 r4 = *(const float4*)&er[dst * 4];
    float ex = l4.x + r4.x, ey = l4.y + r4.y, ez = l4.z + r4.z, ew = l4.w + r4.w;
    ex = (ex >= 0.f) ? ex : NEG_SLOPE * ex;
    ey = (ey >= 0.f) ? ey : NEG_SLOPE * ey;
    ez = (ez >= 0.f) ? ez : NEG_SLOPE * ez;
    ew = (ew >= 0.f) ? ew : NEG_SLOPE * ew;
    float4 s = make_float4(expf(ex), expf(ey), expf(ez), expf(ew));
    int pos = off[dst] + atomicAdd(&cursor[dst], 1);
    ssrc[pos] = src;
    ss[pos] = s;
}

// ---------------------------------------------------------------------------
// Aggregation: one block (256 thr) per dst node, 4-way edge unroll for MLP.
// thread t -> output column t (h = t>>6, d = t&63)
// ---------------------------------------------------------------------------
__global__ __launch_bounds__(256) void k_agg(const int* __restrict__ off,
                                             const int* __restrict__ ssrc,
                                             const float* __restrict__ ss,
                                             const float* __restrict__ fsrc,
                                             float* __restrict__ out) {
    int b = blockIdx.x;
    int t = threadIdx.x;
    int s0 = off[b], s1 = off[b + 1];
    __shared__ float inv_den[HEADS];
    if (t < 64) {
        int h = t & 3;
        float p = 0.f;
        for (int i = s0 + (t >> 2); i < s1; i += 16)
            p += ss[(size_t)i * 4 + h];
        #pragma unroll
        for (int m = 4; m < 64; m <<= 1) p += __shfl_xor(p, m);
        if (t < 4) inv_den[t] = (p > 0.f) ? (1.0f / p) : 0.f;
    }
    __syncthreads();
    int h = t >> 6;
    float idh = inv_den[h];
    float acc = 0.f;
    int i = s0;
    int n4 = s0 + ((s1 - s0) & ~3);
    for (; i < n4; i += 4) {
        int sA = ssrc[i + 0], sB = ssrc[i + 1];
        int sC = ssrc[i + 2], sD = ssrc[i + 3];
        float aA = ss[(size_t)(i + 0) * 4 + h];
        float aB = ss[(size_t)(i + 1) * 4 + h];
        float aC = ss[(size_t)(i + 2) * 4 + h];
        float aD = ss[(size_t)(i + 3) * 4 + h];
        float fA = fsrc[(size_t)sA * NHD + t];
        float fB = fsrc[(size_t)sB * NHD + t];
        float fC = fsrc[(size_t)sC * NHD + t];
        float fD = fsrc[(size_t)sD * NHD + t];
        acc += aA * fA;
        acc += aB * fB;
        acc += aC * fC;
        acc += aD * fD;
    }
    for (; i < s1; ++i) {
        int src = ssrc[i];
        float a = ss[(size_t)i * 4 + h];
        acc += a * fsrc[(size_t)src * NHD + t];
    }
    out[(size_t)b * NHD + t] = acc * idh;
}

// ---------------------------------------------------------------------------
// Launch
// ---------------------------------------------------------------------------
extern "C" void kernel_launch(void* const* d_in, const int* in_sizes, int n_in,
                              void* d_out, int out_size, void* d_ws, size_t ws_size,
                              hipStream_t stream) {
    const float* feat_src = (const float*)d_in[0];
    const float* feat_dst = (const float*)d_in[1];
    const int*   edge_src = (const int*)d_in[2];
    const int*   edge_dst = (const int*)d_in[3];
    const float* W        = (const float*)d_in[4];
    const float* attn_l   = (const float*)d_in[5];
    const float* attn_r   = (const float*)d_in[6];
    float* out = (float*)d_out;

    char* base = (char*)d_ws;
    float* fsrc     = (float*)(base);                         // 102,400,000 B
    float* sorted_s = (float*)(base + 102400000);             //  25,600,000 B
    // Wht/Wlt live at the head of the sorted_s region: k_gemm_mfma reads them
    // strictly before k_scatter (same stream) overwrites the region.
    unsigned short* Wht = (unsigned short*)(base + 102400000);      // 131,072 B
    unsigned short* Wlt = (unsigned short*)(base + 102400000 + 131072);
    float* el       = (float*)(base + 128000000);             //   1,600,000 B
    float* er       = (float*)(base + 129600000);             //   1,600,000 B
    float* wr       = (float*)(base + 131200000);             //       4,096 B
    int*   deg      = (int*)  (base + 131204096);             //     400,000 B
    int*   off      = (int*)  (base + 131604096);             //     400,016 B
    int*   cursor   = (int*)  (base + 132004112);             //     400,000 B
    int*   bsum     = (int*)  (base + 132404112);             //         512 B
    int*   ssrc     = (int*)  (base + 132404624);             //   6,400,000 B

    hipMemsetAsync(deg, 0, N_DST * sizeof(int), stream);
    hipMemsetAsync(cursor, 0, N_DST * sizeof(int), stream);

    k_wr<<<1, 256, 0, stream>>>(W, attn_r, wr);
    k_wcast<<<256, 256, 0, stream>>>(W, Wht, Wlt);
    k_er<<<N_DST / 4, 256, 0, stream>>>(feat_dst, wr, er);
    // fsrc = feat_src @ W  (split-bf16 MFMA) + fused el
    int gblocks = (N_SRC + GBM - 1) / GBM;                    // 782
    k_gemm_mfma<<<gblocks, 512, 0, stream>>>(feat_src, Wht, Wlt, attn_l, fsrc, el);
    // CSR build
    k_hist<<<(N_EDGES + 255) / 256, 256, 0, stream>>>(edge_dst, deg);
    int nb = (N_DST + SCAN_B - 1) / SCAN_B;                   // 98
    k_scanA<<<nb, SCAN_B, 0, stream>>>(deg, off, bsum);
    k_scanB<<<1, 64, 0, stream>>>(bsum, nb);
    k_scanC<<<nb, SCAN_B, 0, stream>>>(off, bsum);
    k_scatter<<<(N_EDGES + 255) / 256, 256, 0, stream>>>(
        edge_src, edge_dst, el, er, off, cursor, ssrc, (float4*)sorted_s);
    // aggregate per dst node
    k_agg<<<N_DST, 256, 0, stream>>>(off, ssrc, sorted_s, fsrc, out);
}

// Round 4
// 726.448 us; speedup vs baseline: 1.3320x; 1.0123x over previous
//
#include <hip/hip_runtime.h>
#include <hip/hip_bf16.h>
#include <math.h>

#define N_SRC   100000
#define N_DST   100000
#define N_EDGES 1600000
#define IN_F    256
#define HEADS   4
#define D_OUT   64
#define NHD     256           // HEADS * D_OUT
#define NEG_SLOPE 0.2f

typedef __attribute__((ext_vector_type(8))) short          bf16x8;
typedef __attribute__((ext_vector_type(8))) unsigned short u16x8;
typedef __attribute__((ext_vector_type(4))) float          f32x4;

// f32 -> bf16 (RNE) + residual bf16
__device__ inline void split_bf16(float x, unsigned short& h, unsigned short& l) {
    unsigned u = __float_as_uint(x);
    unsigned uh = u + (0x7fffu + ((u >> 16) & 1u));
    h = (unsigned short)(uh >> 16);
    float hf = __uint_as_float(uh & 0xffff0000u);
    float r = x - hf;
    unsigned ur = __float_as_uint(r);
    l = (unsigned short)((ur + (0x7fffu + ((ur >> 16) & 1u))) >> 16);
}

// ---------------------------------------------------------------------------
// Kernel 1: wr[k][h] = sum_d W[k][h*64+d] * attn_r[h][d]   (256x4 result)
// ---------------------------------------------------------------------------
__global__ void k_wr(const float* __restrict__ W, const float* __restrict__ ar,
                     float* __restrict__ wr) {
    __shared__ float a[NHD];
    int t = threadIdx.x;                 // 256 threads, 1 block
    a[t] = ar[t];
    __syncthreads();
    float s[HEADS] = {0.f, 0.f, 0.f, 0.f};
    for (int h = 0; h < HEADS; ++h) {
        float acc = 0.f;
        #pragma unroll 8
        for (int d = 0; d < D_OUT; ++d)
            acc += W[t * NHD + h * D_OUT + d] * a[h * D_OUT + d];
        s[h] = acc;
    }
    *(float4*)&wr[t * 4] = make_float4(s[0], s[1], s[2], s[3]);
}

// ---------------------------------------------------------------------------
// Kernel 1b: W -> transposed hi/lo bf16:  Wht[n][k], Wlt[n][k]
// ---------------------------------------------------------------------------
__global__ void k_wcast(const float* __restrict__ W,
                        unsigned short* __restrict__ Wht,
                        unsigned short* __restrict__ Wlt) {
    int n = blockIdx.x;      // 256 blocks
    int k = threadIdx.x;     // 256 threads
    float x = W[k * NHD + n];
    unsigned short h, l;
    split_bf16(x, h, l);
    Wht[n * IN_F + k] = h;
    Wlt[n * IN_F + k] = l;
}

// ---------------------------------------------------------------------------
// Kernel 2: er[n][h] = sum_k feat_dst[n][k] * wr[k][h]   (one wave per node)
// ---------------------------------------------------------------------------
__global__ __launch_bounds__(256) void k_er(const float* __restrict__ fdst,
                                            const float* __restrict__ wr,
                                            float* __restrict__ er) {
    __shared__ float4 wrs[256];
    int t = threadIdx.x;
    wrs[t] = ((const float4*)wr)[t];
    __syncthreads();
    int node = blockIdx.x * 4 + (t >> 6);
    int lane = t & 63;
    float4 f = *(const float4*)&fdst[(size_t)node * IN_F + lane * 4];
    float4 w0 = wrs[lane * 4 + 0], w1 = wrs[lane * 4 + 1];
    float4 w2 = wrs[lane * 4 + 2], w3 = wrs[lane * 4 + 3];
    float px = f.x * w0.x + f.y * w1.x + f.z * w2.x + f.w * w3.x;
    float py = f.x * w0.y + f.y * w1.y + f.z * w2.y + f.w * w3.y;
    float pz = f.x * w0.z + f.y * w1.z + f.z * w2.z + f.w * w3.z;
    float pw = f.x * w0.w + f.y * w1.w + f.z * w2.w + f.w * w3.w;
    #pragma unroll
    for (int m = 1; m < 64; m <<= 1) {
        px += __shfl_xor(px, m);
        py += __shfl_xor(py, m);
        pz += __shfl_xor(pz, m);
        pw += __shfl_xor(pw, m);
    }
    if (lane == 0)
        *(float4*)&er[node * 4] = make_float4(px, py, pz, pw);
}

// ---------------------------------------------------------------------------
// Kernel 3: fsrc = feat_src @ W via split-bf16 MFMA (3 products, fp32 acc)
//           + fused el[n][h] epilogue.
// BM=128, BN=256(all of N), BK=32, 512 thr = 8 waves (2Mx4N), wave tile 64x64.
// ---------------------------------------------------------------------------
#define GBM 128
#define GBK 32
__global__ __launch_bounds__(512, 2) void k_gemm_mfma(
        const float* __restrict__ A, const unsigned short* __restrict__ Bht,
        const unsigned short* __restrict__ Blt, const float* __restrict__ al_g,
        float* __restrict__ C, float* __restrict__ el) {
    __shared__ __align__(16) unsigned short Ah[GBM][GBK], Al[GBM][GBK];
    __shared__ __align__(16) unsigned short Bh[NHD][GBK], Bl[NHD][GBK];
    const int t = threadIdx.x;
    const int m0 = blockIdx.x * GBM;
    const int wid = t >> 6, lane = t & 63;
    const int wm = wid >> 2, wn = wid & 3;       // wave tile: rows wm*64, cols wn*64
    const int fr = lane & 15, fq = lane >> 4;
    const int kb = fq * 8;                        // k-offset of this lane's frag

    f32x4 acc[4][4];
    #pragma unroll
    for (int m = 0; m < 4; ++m)
        #pragma unroll
        for (int n = 0; n < 4; ++n)
            acc[m][n] = (f32x4){0.f, 0.f, 0.f, 0.f};

    // staging assignments
    const int ar = t >> 2, ac = (t & 3) * 8;      // A: row 0..127, col {0,8,16,24}
    const bool avalid = (m0 + ar) < N_SRC;
    const float* aptr = A + (size_t)(m0 + ar) * IN_F + ac;
    const int bn = t >> 1, bk = (t & 1) * 16;     // B: n 0..255, k {0,16}

    for (int k0 = 0; k0 < IN_F; k0 += GBK) {
        // ---- load globals to regs ----
        float4 v0 = make_float4(0.f, 0.f, 0.f, 0.f), v1 = v0;
        if (avalid) {
            v0 = *(const float4*)(aptr + k0);
            v1 = *(const float4*)(aptr + k0 + 4);
        }
        u16x8 bh0 = *(const u16x8*)(Bht + (size_t)bn * IN_F + k0 + bk);
        u16x8 bh1 = *(const u16x8*)(Bht + (size_t)bn * IN_F + k0 + bk + 8);
        u16x8 bl0 = *(const u16x8*)(Blt + (size_t)bn * IN_F + k0 + bk);
        u16x8 bl1 = *(const u16x8*)(Blt + (size_t)bn * IN_F + k0 + bk + 8);
        // ---- convert A to hi/lo ----
        float xs[8] = {v0.x, v0.y, v0.z, v0.w, v1.x, v1.y, v1.z, v1.w};
        u16x8 hv, lv;
        #pragma unroll
        for (int j = 0; j < 8; ++j) {
            unsigned short hh, ll;
            split_bf16(xs[j], hh, ll);
            hv[j] = hh; lv[j] = ll;
        }
        __syncthreads();                 // readers of previous chunk done
        *(u16x8*)&Ah[ar][ac] = hv;
        *(u16x8*)&Al[ar][ac] = lv;
        *(u16x8*)&Bh[bn][bk]     = bh0;
        *(u16x8*)&Bh[bn][bk + 8] = bh1;
        *(u16x8*)&Bl[bn][bk]     = bl0;
        *(u16x8*)&Bl[bn][bk + 8] = bl1;
        __syncthreads();                 // writes visible
        // ---- fragments ----
        bf16x8 afh[4], afl[4], bfh[4], bfl[4];
        #pragma unroll
        for (int m = 0; m < 4; ++m) {
            afh[m] = *(const bf16x8*)&Ah[wm * 64 + m * 16 + fr][kb];
            afl[m] = *(const bf16x8*)&Al[wm * 64 + m * 16 + fr][kb];
        }
        #pragma unroll
        for (int n = 0; n < 4; ++n) {
            bfh[n] = *(const bf16x8*)&Bh[wn * 64 + n * 16 + fr][kb];
            bfl[n] = *(const bf16x8*)&Bl[wn * 64 + n * 16 + fr][kb];
        }
        #pragma unroll
        for (int m = 0; m < 4; ++m)
            #pragma unroll
            for (int n = 0; n < 4; ++n) {
                acc[m][n] = __builtin_amdgcn_mfma_f32_16x16x32_bf16(afh[m], bfh[n], acc[m][n], 0, 0, 0);
                acc[m][n] = __builtin_amdgcn_mfma_f32_16x16x32_bf16(afh[m], bfl[n], acc[m][n], 0, 0, 0);
                acc[m][n] = __builtin_amdgcn_mfma_f32_16x16x32_bf16(afl[m], bfh[n], acc[m][n], 0, 0, 0);
            }
    }

    // ---- epilogue: store C + fused el (this wave's 64 cols == head wn) ----
    float alw[4];
    #pragma unroll
    for (int n = 0; n < 4; ++n) alw[n] = al_g[wn * 64 + n * 16 + fr];
    #pragma unroll
    for (int m = 0; m < 4; ++m) {
        int rbase = m0 + wm * 64 + m * 16 + fq * 4;
        float elp[4] = {0.f, 0.f, 0.f, 0.f};
        #pragma unroll
        for (int n = 0; n < 4; ++n) {
            f32x4 a = acc[m][n];
            int col = wn * 64 + n * 16 + fr;
            float w = alw[n];
            elp[0] += a[0] * w; elp[1] += a[1] * w;
            elp[2] += a[2] * w; elp[3] += a[3] * w;
            #pragma unroll
            for (int j = 0; j < 4; ++j)
                if (rbase + j < N_SRC)
                    C[(size_t)(rbase + j) * NHD + col] = a[j];
        }
        #pragma unroll
        for (int j = 0; j < 4; ++j) {
            float s = elp[j];
            s += __shfl_xor(s, 1); s += __shfl_xor(s, 2);
            s += __shfl_xor(s, 4); s += __shfl_xor(s, 8);
            if (fr == 0 && rbase + j < N_SRC)
                el[(rbase + j) * HEADS + wn] = s;
        }
    }
}

// ---------------------------------------------------------------------------
// Edge histogram over dst
// ---------------------------------------------------------------------------
__global__ void k_hist(const int* __restrict__ edst, int* __restrict__ deg) {
    int e = blockIdx.x * 256 + threadIdx.x;
    if (e < N_EDGES) atomicAdd(&deg[edst[e]], 1);
}

// ---------------------------------------------------------------------------
// 3-kernel exclusive scan over deg[N_DST] -> off[N_DST+1]
// ---------------------------------------------------------------------------
#define SCAN_B 1024
__global__ __launch_bounds__(SCAN_B) void k_scanA(const int* __restrict__ deg,
                                                  int* __restrict__ off,
                                                  int* __restrict__ bsum) {
    int t = threadIdx.x, b = blockIdx.x;
    int i = b * SCAN_B + t;
    int v = (i < N_DST) ? deg[i] : 0;
    int incl = v;
    int lane = t & 63, w = t >> 6;
    #pragma unroll
    for (int d = 1; d < 64; d <<= 1) {
        int u = __shfl_up(incl, d);
        if (lane >= d) incl += u;
    }
    __shared__ int ws[16];
    if (lane == 63) ws[w] = incl;
    __syncthreads();
    if (t == 0) {
        int run = 0;
        for (int j = 0; j < 16; ++j) { int x = ws[j]; ws[j] = run; run += x; }
        bsum[b] = run;
    }
    __syncthreads();
    if (i < N_DST) off[i] = incl - v + ws[w];
}

__global__ void k_scanB(int* __restrict__ bsum, int nb) {
    if (threadIdx.x == 0 && blockIdx.x == 0) {
        int run = 0;
        for (int j = 0; j < nb; ++j) { int x = bsum[j]; bsum[j] = run; run += x; }
    }
}

__global__ __launch_bounds__(SCAN_B) void k_scanC(int* __restrict__ off,
                                                  const int* __restrict__ bsum) {
    int t = threadIdx.x, b = blockIdx.x;
    int i = b * SCAN_B + t;
    if (i < N_DST) off[i] += bsum[b];
    if (i == 0) off[N_DST] = N_EDGES;
}

// ---------------------------------------------------------------------------
// Scatter: counting-sort edges by dst; compute s = exp(leaky(el[src]+er[dst]))
// ---------------------------------------------------------------------------
__global__ void k_scatter(const int* __restrict__ esrc, const int* __restrict__ edst,
                          const float* __restrict__ el, const float* __restrict__ er,
                          const int* __restrict__ off, int* __restrict__ cursor,
                          int* __restrict__ ssrc, float4* __restrict__ ss) {
    int e = blockIdx.x * 256 + threadIdx.x;
    if (e >= N_EDGES) return;
    int src = esrc[e], dst = edst[e];
    float4 l4 = *(const float4*)&el[src * 4];
    float4 r4 = *(const float4*)&er[dst * 4];
    float ex = l4.x + r4.x, ey = l4.y + r4.y, ez = l4.z + r4.z, ew = l4.w + r4.w;
    ex = (ex >= 0.f) ? ex : NEG_SLOPE * ex;
    ey = (ey >= 0.f) ? ey : NEG_SLOPE * ey;
    ez = (ez >= 0.f) ? ez : NEG_SLOPE * ez;
    ew = (ew >= 0.f) ? ew : NEG_SLOPE * ew;
    float4 s = make_float4(expf(ex), expf(ey), expf(ez), expf(ew));
    int pos = off[dst] + atomicAdd(&cursor[dst], 1);
    ssrc[pos] = src;
    ss[pos] = s;
}

// ---------------------------------------------------------------------------
// Aggregation: one block (256 thr = 4 waves) per dst node.
// Wave w handles edges s0+w, s0+w+4, ... : full 256-col row per edge,
// float4 per lane (16B), 2-deep unroll => 8 x 1KB gathers in flight / block.
// Cross-wave combine via 4KB LDS at the end. No float atomics.
// ---------------------------------------------------------------------------
__global__ __launch_bounds__(256) void k_agg(const int* __restrict__ off,
                                             const int* __restrict__ ssrc,
                                             const float* __restrict__ ss,
                                             const float* __restrict__ fsrc,
                                             float* __restrict__ out) {
    int b = blockIdx.x;
    int t = threadIdx.x;
    int s0 = off[b], s1 = off[b + 1];
    int w = t >> 6, lane = t & 63;
    int h = lane >> 4;                   // head for this lane's 4 cols
    int col = lane << 2;                 // 4*lane .. 4*lane+3 (same head)

    __shared__ float inv_den[HEADS];
    __shared__ float red[4][NHD];

    // denominator: 64 threads, 16 per head component
    if (t < 64) {
        int hh = t & 3;
        float p = 0.f;
        for (int i = s0 + (t >> 2); i < s1; i += 16)
            p += ss[(size_t)i * 4 + hh];
        #pragma unroll
        for (int m = 4; m < 64; m <<= 1) p += __shfl_xor(p, m);
        if (t < 4) inv_den[t] = (p > 0.f) ? (1.0f / p) : 0.f;
    }

    // main gather: wave-per-edge, float4 per lane
    float4 acc = make_float4(0.f, 0.f, 0.f, 0.f);
    int i = s0 + w;
    for (; i + 4 < s1; i += 8) {
        int   srcA = ssrc[i];
        int   srcB = ssrc[i + 4];
        float aA = ss[(size_t)i * 4 + h];
        float aB = ss[(size_t)(i + 4) * 4 + h];
        float4 fA = *(const float4*)&fsrc[(size_t)srcA * NHD + col];
        float4 fB = *(const float4*)&fsrc[(size_t)srcB * NHD + col];
        acc.x += aA * fA.x; acc.y += aA * fA.y;
        acc.z += aA * fA.z; acc.w += aA * fA.w;
        acc.x += aB * fB.x; acc.y += aB * fB.y;
        acc.z += aB * fB.z; acc.w += aB * fB.w;
    }
    if (i < s1) {
        int   src = ssrc[i];
        float a   = ss[(size_t)i * 4 + h];
        float4 f  = *(const float4*)&fsrc[(size_t)src * NHD + col];
        acc.x += a * f.x; acc.y += a * f.y;
        acc.z += a * f.z; acc.w += a * f.w;
    }
    *(float4*)&red[w][col] = acc;
    __syncthreads();

    // combine 4 waves + scale; thread t owns output col t
    float r = red[0][t] + red[1][t] + red[2][t] + red[3][t];
    out[(size_t)b * NHD + t] = r * inv_den[t >> 6];
}

// ---------------------------------------------------------------------------
// Launch
// ---------------------------------------------------------------------------
extern "C" void kernel_launch(void* const* d_in, const int* in_sizes, int n_in,
                              void* d_out, int out_size, void* d_ws, size_t ws_size,
                              hipStream_t stream) {
    const float* feat_src = (const float*)d_in[0];
    const float* feat_dst = (const float*)d_in[1];
    const int*   edge_src = (const int*)d_in[2];
    const int*   edge_dst = (const int*)d_in[3];
    const float* W        = (const float*)d_in[4];
    const float* attn_l   = (const float*)d_in[5];
    const float* attn_r   = (const float*)d_in[6];
    float* out = (float*)d_out;

    char* base = (char*)d_ws;
    float* fsrc     = (float*)(base);                         // 102,400,000 B
    float* sorted_s = (float*)(base + 102400000);             //  25,600,000 B
    // Wht/Wlt live at the head of the sorted_s region: k_gemm_mfma reads them
    // strictly before k_scatter (same stream) overwrites the region.
    unsigned short* Wht = (unsigned short*)(base + 102400000);      // 131,072 B
    unsigned short* Wlt = (unsigned short*)(base + 102400000 + 131072);
    float* el       = (float*)(base + 128000000);             //   1,600,000 B
    float* er       = (float*)(base + 129600000);             //   1,600,000 B
    float* wr       = (float*)(base + 131200000);             //       4,096 B
    int*   deg      = (int*)  (base + 131204096);             //     400,000 B
    int*   off      = (int*)  (base + 131604096);             //     400,016 B
    int*   cursor   = (int*)  (base + 132004112);             //     400,000 B
    int*   bsum     = (int*)  (base + 132404112);             //         512 B
    int*   ssrc     = (int*)  (base + 132404624);             //   6,400,000 B

    hipMemsetAsync(deg, 0, N_DST * sizeof(int), stream);
    hipMemsetAsync(cursor, 0, N_DST * sizeof(int), stream);

    k_wr<<<1, 256, 0, stream>>>(W, attn_r, wr);
    k_wcast<<<256, 256, 0, stream>>>(W, Wht, Wlt);
    k_er<<<N_DST / 4, 256, 0, stream>>>(feat_dst, wr, er);
    // fsrc = feat_src @ W  (split-bf16 MFMA) + fused el
    int gblocks = (N_SRC + GBM - 1) / GBM;                    // 782
    k_gemm_mfma<<<gblocks, 512, 0, stream>>>(feat_src, Wht, Wlt, attn_l, fsrc, el);
    // CSR build
    k_hist<<<(N_EDGES + 255) / 256, 256, 0, stream>>>(edge_dst, deg);
    int nb = (N_DST + SCAN_B - 1) / SCAN_B;                   // 98
    k_scanA<<<nb, SCAN_B, 0, stream>>>(deg, off, bsum);
    k_scanB<<<1, 64, 0, stream>>>(bsum, nb);
    k_scanC<<<nb, SCAN_B, 0, stream>>>(off, bsum);
    k_scatter<<<(N_EDGES + 255) / 256, 256, 0, stream>>>(
        edge_src, edge_dst, el, er, off, cursor, ssrc, (float4*)sorted_s);
    // aggregate per dst node
    k_agg<<<N_DST, 256, 0, stream>>>(off, ssrc, sorted_s, fsrc, out);
}